// Round 10
// baseline (256.218 us; speedup 1.0000x reference)
//
#include <hip/hip_runtime.h>
#include <math.h>

#define Bb 4
#define Tt 2048
#define Cc 1024
#define Hh 16
#define Dd 64
#define QSC 0.18033688011112042f   // (1/sqrt(64)) * log2(e)

typedef unsigned short ushort_t;
typedef __attribute__((ext_vector_type(8))) short short8;
typedef __attribute__((ext_vector_type(4))) float floatx4;

typedef unsigned int __attribute__((address_space(1))) u32_as1;
typedef unsigned int __attribute__((address_space(3))) u32_as3;

__device__ __forceinline__ void gld_lds16(const void* g, const void* lds_uniform) {
    __builtin_amdgcn_global_load_lds(
        (const u32_as1*)(unsigned long long)g,
        (u32_as3*)(unsigned int)(unsigned long long)lds_uniform,
        16, 0, 0);
}

__device__ inline ushort_t f2bf(float x) {
    unsigned int u = __float_as_uint(x);
    return (ushort_t)((u + 0x7FFFu + ((u >> 16) & 1u)) >> 16);
}

__device__ __forceinline__ void bar() {
    asm volatile("" ::: "memory");
    __builtin_amdgcn_s_barrier();
    asm volatile("" ::: "memory");
}

// ---------------- x fp32 -> bf16 ----------------
__global__ __launch_bounds__(256) void convert_kernel(
    const float* __restrict__ in, ushort_t* __restrict__ out, int n4)
{
    int i = blockIdx.x * 256 + threadIdx.x;
    if (i < n4) {
        float4 v = *(const float4*)&in[i * 4];
        ushort_t o[4] = {f2bf(v.x), f2bf(v.y), f2bf(v.z), f2bf(v.w)};
        *(uint2*)&out[i * 4] = *(uint2*)o;
    }
}

// ---------------- W [K][N] fp32 -> Wt [N][K] bf16 ----------------
__global__ __launch_bounds__(256) void transpose_kernel(
    const float* __restrict__ W, ushort_t* __restrict__ Wt, int K, int N)
{
    __shared__ ushort_t Ts[16][72];
    const int n0 = blockIdx.x * 64;
    const int k0 = blockIdx.y * 16;
    const int t = threadIdx.x;
#pragma unroll
    for (int i = 0; i < 4; i++) {
        int e = t + i * 256;
        int kl = e >> 6, nl = e & 63;
        Ts[kl][nl] = f2bf(W[(size_t)(k0 + kl) * N + n0 + nl]);
    }
    __syncthreads();
    {
        int nl = t >> 2, kl4 = (t & 3) * 4;
        ushort_t o[4] = {Ts[kl4][nl], Ts[kl4 + 1][nl], Ts[kl4 + 2][nl], Ts[kl4 + 3][nl]};
        *(uint2*)&Wt[(size_t)(n0 + nl) * K + k0 + kl4] = *(uint2*)o;
    }
}

// ---------------- 128x256 2-phase bf16 MFMA GEMM ----------------
template <bool OUT_BF16, bool SCALE_Q>
__global__ __launch_bounds__(512) void gemm128_kernel(
    const ushort_t* __restrict__ A, const ushort_t* __restrict__ Bt,
    const float* __restrict__ bias, void* __restrict__ Co,
    int M, int N, int K)
{
    __shared__ __align__(16) ushort_t Ls[49152];   // 96 KiB: 2 slots x 3 x 8192

    const int tid = threadIdx.x;
    const int lane = tid & 63;
    const int w = tid >> 6;              // 0..7
    const int wm = w >> 2, wn = w & 3;   // wave grid 2m x 4n
    const int l = lane & 15, q = lane >> 4;
    const int NT = K >> 6;               // K-tiles of 64

    const int n0 = blockIdx.x * 256;
    const int m0 = blockIdx.y * 128;

    const int ln = lane ^ (((lane >> 5) & 1) << 1);
    const ushort_t* Ag = A  + (size_t)(m0 + w * 16 + (ln >> 2)) * K + (ln & 3) * 8;
    const ushort_t* Bg = Bt + (size_t)(n0 + w * 16 + (ln >> 2)) * K + (ln & 3) * 8;

    const int swz = l * 32 + ((q * 8) ^ (((l >> 3) & 1) << 4));

    floatx4 acc[2][4][2];
#pragma unroll
    for (int qn = 0; qn < 2; qn++)
#pragma unroll
        for (int mf = 0; mf < 4; mf++)
#pragma unroll
            for (int nf = 0; nf < 2; nf++)
                acc[qn][mf][nf] = (floatx4){0.f, 0.f, 0.f, 0.f};

    short8 af[4][2], bf0[2][2], bf1[2][2];

#define STAGE_A(SLOT, T) {                                                      \
    const ushort_t* _g = Ag + (size_t)(T) * 64;                                 \
    const ushort_t* _l = &Ls[(SLOT) * 24576 + w * 1024];                        \
    gld_lds16(_g, _l);                                                          \
    gld_lds16(_g + 32, _l + 512); }
#define STAGE_B(SLOT, H, T) {                                                   \
    const ushort_t* _g = Bg + (size_t)(H) * 128 * K + (size_t)(T) * 64;         \
    const ushort_t* _l = &Ls[(SLOT) * 24576 + (1 + (H)) * 8192 + w * 1024];     \
    gld_lds16(_g, _l);                                                          \
    gld_lds16(_g + 32, _l + 512); }

#define LDA(SLOT) {                                                             \
    _Pragma("unroll") for (int mf = 0; mf < 4; mf++)                            \
    _Pragma("unroll") for (int kc = 0; kc < 2; kc++)                            \
        af[mf][kc] = *(const short8*)&Ls[(SLOT) * 24576 +                       \
            ((wm * 4 + mf) * 2 + kc) * 512 + swz]; }

#define LDB(SLOT, QN, DST) {                                                    \
    _Pragma("unroll") for (int nf = 0; nf < 2; nf++)                            \
    _Pragma("unroll") for (int kc = 0; kc < 2; kc++)                            \
        DST[nf][kc] = *(const short8*)&Ls[(SLOT) * 24576 + (1 + (QN)) * 8192 +  \
            ((wn * 2 + nf) * 2 + kc) * 512 + swz]; }

#define MM(QN, BF) {                                                            \
    __builtin_amdgcn_s_setprio(1);                                              \
    _Pragma("unroll") for (int kc = 0; kc < 2; kc++)                            \
    _Pragma("unroll") for (int mf = 0; mf < 4; mf++)                            \
    _Pragma("unroll") for (int nf = 0; nf < 2; nf++)                            \
        acc[QN][mf][nf] = __builtin_amdgcn_mfma_f32_16x16x32_bf16(              \
            af[mf][kc], BF[nf][kc], acc[QN][mf][nf], 0, 0, 0);                  \
    __builtin_amdgcn_s_setprio(0); }

#define LGKM0() asm volatile("s_waitcnt lgkmcnt(0)" ::: "memory")

    // prologue: T0 fully (A,B0,B1), T1 partial (A,B0); wait T0 landed
    STAGE_A(0, 0); STAGE_B(0, 0, 0); STAGE_B(0, 1, 0);
    if (NT > 1) {
        STAGE_A(1, 1); STAGE_B(1, 0, 1);
        asm volatile("s_waitcnt vmcnt(4)" ::: "memory");
    } else {
        asm volatile("s_waitcnt vmcnt(0)" ::: "memory");
    }
    bar();

    for (int g = 0; g < NT; ++g) {
        const int slot = g & 1;

        // phase 1: quadrant qn=0 — reads A, B0
        LDA(slot);
        LDB(slot, 0, bf0);
        if (g + 1 < NT) STAGE_B(slot ^ 1, 1, g + 1);   // B1 of next tile
        bar();
        LGKM0();
        MM(0, bf0);
        bar();

        // phase 2: quadrant qn=1 — reads B1 (A frags reused)
        LDB(slot, 1, bf1);
        if (g + 2 < NT) { STAGE_A(slot, g + 2); STAGE_B(slot, 0, g + 2); }
        bar();
        LGKM0();
        MM(1, bf1);
        if (g + 1 < NT) {
            if (g + 2 < NT) asm volatile("s_waitcnt vmcnt(4)" ::: "memory");
            else            asm volatile("s_waitcnt vmcnt(0)" ::: "memory");
            bar();
        }
    }

    // epilogue
#pragma unroll
    for (int qn = 0; qn < 2; qn++)
#pragma unroll
        for (int nf = 0; nf < 2; nf++) {
            const int col = n0 + qn * 128 + wn * 32 + nf * 16 + l;
            const float bi = bias[col];
            const float sc = (SCALE_Q && col < 1024) ? QSC : 1.0f;
#pragma unroll
            for (int mf = 0; mf < 4; mf++)
#pragma unroll
                for (int r = 0; r < 4; r++) {
                    const int row = m0 + wm * 64 + mf * 16 + q * 4 + r;
                    const float v = (acc[qn][mf][nf][r] + bi) * sc;
                    if (OUT_BF16)
                        ((ushort_t*)Co)[(size_t)row * N + col] = f2bf(v);
                    else
                        ((float*)Co)[(size_t)row * N + col] = v;
                }
        }
#undef STAGE_A
#undef STAGE_B
#undef LDA
#undef LDB
#undef MM
#undef LGKM0
}

// ---------------- attn LDS swizzle helpers ----------------
__device__ __forceinline__ int ks_swz(int I) {
    return I ^ (((I >> 8) & 1) * 0x28) ^ (((I >> 9) & 1) * 0x10);
}
__device__ __forceinline__ int vt_idx(int row, int col) {
    return row * 80 + (col ^ ((((row >> 2) ^ (row >> 4)) & 3) << 3));
}

#define KS_SLOT 4096   // ushorts per Ks slot (64 keys x 64 d)
#define VT_SLOT 5120   // ushorts per Vt slot (64 d-rows x 80 stride)

// ---------------- bf16 MFMA flash attention: swapped-QK, KVBLK=128 pairs ----
// Grid: (64 bh, 16 q-tiles), heavy-first. Block: 4 waves, one 128-row q-tile.
// Round 9 showed all pipes <40% busy (dependency-latency bound). This round:
// two independent 64-key sub-tiles (A,B) per barrier. In-register softmax
// (swapped S=mfma(K,Q), lane-local P) makes the 4 SM_PV chains register-local
// and independent => PV_A MFMAs overlap SM_B exp/pack VALU. Barriers per block
// halve (2j+3 -> j+2). 4 K/V slots = double-buffered pairs, LDS 73,728 B
// (2 blocks/CU). launch_bounds STAYS (256,2): (256,3) forced VGPR 84 + 125 MB
// spill (r7), (256,4) VGPR 64 + 377 MB (r2). Spill tripwire: WRITE_SIZE 16 MB.
__global__ __launch_bounds__(256, 2) void attn_mfma_kernel(
    const ushort_t* __restrict__ qkv, ushort_t* __restrict__ yatt)
{
    __shared__ __align__(16) ushort_t Ks[4 * KS_SLOT];
    __shared__ __align__(16) ushort_t Vt[4 * VT_SLOT];

    const int tid = threadIdx.x;
    const int lane = tid & 63;
    const int w = tid >> 6;
    const int quad = lane >> 4;
    const int l = lane & 15;

    const int bh = blockIdx.x;
    const int j = 15 - (int)blockIdx.y;        // heavy-first dispatch
    const int q0 = j * 128;
    const int b = bh >> 4;
    const int h = bh & 15;
    const size_t base = (size_t)b * Tt * (3 * Cc);
    const int qoff = h * 64;
    const int koff = Cc + h * 64;
    const int voff = 2 * Cc + h * 64;

    // Q fragments (pre-scaled by QSC in the GEMM epilogue)
    short8 Qf[2][2];
#pragma unroll
    for (int mt = 0; mt < 2; mt++)
#pragma unroll
        for (int kc = 0; kc < 2; kc++)
            Qf[mt][kc] = *(const short8*)&qkv[base
                + (size_t)(q0 + mt * 64 + w * 16 + l) * (3 * Cc)
                + qoff + kc * 32 + quad * 8];

    floatx4 Oacc[2][4];
    float Lacc[2] = {0.f, 0.f};
#pragma unroll
    for (int mt = 0; mt < 2; mt++)
#pragma unroll
        for (int dt = 0; dt < 4; dt++)
            Oacc[mt][dt] = (floatx4){0.f, 0.f, 0.f, 0.f};

    const int srow = tid >> 2;            // key row 0..63 within a sub-tile
    const int sd0 = (tid & 3) * 16;       // d chunk
    const int knt = srow >> 4, kl = srow & 15;
    const int kc_s = sd0 >> 5;
    const int qp0 = (sd0 & 31) >> 3;
    // PV contraction permutation: key srow stored at column pcol
    const int pcol = 32 * (srow >> 5) + 8 * ((srow >> 2) & 3)
                   + 4 * ((srow >> 4) & 1) + (srow & 3);

    const int npair = j + 1;              // ntil = 2j+2, always even

    const ushort_t* kp0 = &qkv[base + (size_t)srow * (3 * Cc) + koff + sd0];
    const ushort_t* vp0 = &qkv[base + (size_t)srow * (3 * Cc) + voff + sd0];

    const int ksw0 = ks_swz((knt * 2 + kc_s) * 512 + (qp0 * 16 + kl) * 8);
    const int ksw1 = ks_swz((knt * 2 + kc_s) * 512 + ((qp0 + 1) * 16 + kl) * 8);

    uint4 pk00, pk01, pv00, pv01;   // sub A prefetch
    uint4 pk10, pk11, pv10, pv11;   // sub B prefetch

#define LOAD_PAIR(P) {                                                          \
    const size_t _o0 = (size_t)((P) * 128) * (3 * Cc);                          \
    const size_t _o1 = _o0 + (size_t)64 * (3 * Cc);                             \
    pk00 = *(const uint4*)(kp0 + _o0); pk01 = *(const uint4*)(kp0 + _o0 + 8);   \
    pv00 = *(const uint4*)(vp0 + _o0); pv01 = *(const uint4*)(vp0 + _o0 + 8);   \
    pk10 = *(const uint4*)(kp0 + _o1); pk11 = *(const uint4*)(kp0 + _o1 + 8);   \
    pv10 = *(const uint4*)(vp0 + _o1); pv11 = *(const uint4*)(vp0 + _o1 + 8); }

#define WRITE_TILE(SLOT, PK0, PK1, PV0, PV1) {                                  \
    *(uint4*)&Ks[(SLOT) * KS_SLOT + ksw0] = PK0;                                \
    *(uint4*)&Ks[(SLOT) * KS_SLOT + ksw1] = PK1;                                \
    ushort_t tv[16];                                                            \
    *(uint4*)&tv[0] = PV0;                                                      \
    *(uint4*)&tv[8] = PV1;                                                      \
    _Pragma("unroll") for (int t2 = 0; t2 < 16; t2++)                           \
        Vt[(SLOT) * VT_SLOT + vt_idx(sd0 + t2, pcol)] = tv[t2]; }

#define WRITE_PAIR(SB) {                                                        \
    WRITE_TILE((SB), pk00, pk01, pv00, pv01);                                   \
    WRITE_TILE((SB) + 1, pk10, pk11, pv10, pv11); }

// swapped QK^T over one 64-key sub-tile in LDS slot SLOT
#define QK(SLOT, S1, S0, ACT0) {                                                \
    _Pragma("unroll") for (int nt = 0; nt < 4; nt++)                            \
        S1[nt] = (floatx4){0.f, 0.f, 0.f, 0.f};                                 \
    __builtin_amdgcn_s_setprio(1);                                              \
    if (ACT0) {                                                                 \
        _Pragma("unroll") for (int nt = 0; nt < 4; nt++)                        \
            S0[nt] = (floatx4){0.f, 0.f, 0.f, 0.f};                             \
        _Pragma("unroll") for (int kc = 0; kc < 2; kc++)                        \
        _Pragma("unroll") for (int nt = 0; nt < 4; nt++) {                      \
            short8 kf = *(const short8*)&Ks[(SLOT) * KS_SLOT                    \
                + ks_swz((nt * 2 + kc) * 512 + lane * 8)];                      \
            S1[nt] = __builtin_amdgcn_mfma_f32_16x16x32_bf16(                   \
                kf, Qf[1][kc], S1[nt], 0, 0, 0);                                \
            S0[nt] = __builtin_amdgcn_mfma_f32_16x16x32_bf16(                   \
                kf, Qf[0][kc], S0[nt], 0, 0, 0);                                \
        }                                                                       \
    } else {                                                                    \
        _Pragma("unroll") for (int kc = 0; kc < 2; kc++)                        \
        _Pragma("unroll") for (int nt = 0; nt < 4; nt++) {                      \
            short8 kf = *(const short8*)&Ks[(SLOT) * KS_SLOT                    \
                + ks_swz((nt * 2 + kc) * 512 + lane * 8)];                      \
            S1[nt] = __builtin_amdgcn_mfma_f32_16x16x32_bf16(                   \
                kf, Qf[1][kc], S1[nt], 0, 0, 0);                                \
        }                                                                       \
    }                                                                           \
    __builtin_amdgcn_s_setprio(0); }

// in-register softmax + PV for one (mt, sub-tile): lane's q-row = qmin + l
#define SM_PV(SV, MT, KB, VF) {                                                 \
    const int qrow = q0 + (MT) * 64 + (w << 4) + l;                             \
    const bool needm = ((KB) + 63 > q0 + (MT) * 64 + (w << 4));                 \
    float lsum = 0.f;                                                           \
    unsigned int pw[8];                                                         \
    _Pragma("unroll") for (int nt = 0; nt < 4; nt++) {                          \
        float e[4];                                                             \
        _Pragma("unroll") for (int r = 0; r < 4; r++) {                         \
            float s2 = SV[nt][r];                                               \
            if (needm && ((KB) + nt * 16 + quad * 4 + r > qrow))                \
                s2 = -INFINITY;                                                 \
            e[r] = __builtin_amdgcn_exp2f(s2);                                  \
            lsum += e[r];                                                       \
        }                                                                       \
        pw[nt * 2 + 0] = __builtin_amdgcn_perm(                                 \
            __float_as_uint(e[1]), __float_as_uint(e[0]), 0x07060302u);         \
        pw[nt * 2 + 1] = __builtin_amdgcn_perm(                                 \
            __float_as_uint(e[3]), __float_as_uint(e[2]), 0x07060302u);         \
    }                                                                           \
    lsum += __shfl_xor(lsum, 16);                                               \
    lsum += __shfl_xor(lsum, 32);                                               \
    Lacc[MT] += lsum;                                                           \
    uint4 _u0; _u0.x = pw[0]; _u0.y = pw[1]; _u0.z = pw[2]; _u0.w = pw[3];      \
    uint4 _u1; _u1.x = pw[4]; _u1.y = pw[5]; _u1.z = pw[6]; _u1.w = pw[7];      \
    short8 Pa0 = __builtin_bit_cast(short8, _u0);                               \
    short8 Pa1 = __builtin_bit_cast(short8, _u1);                               \
    __builtin_amdgcn_s_setprio(1);                                              \
    _Pragma("unroll") for (int dt = 0; dt < 4; dt++) {                          \
        Oacc[MT][dt] = __builtin_amdgcn_mfma_f32_16x16x32_bf16(                 \
            Pa0, VF[dt][0], Oacc[MT][dt], 0, 0, 0);                             \
        Oacc[MT][dt] = __builtin_amdgcn_mfma_f32_16x16x32_bf16(                 \
            Pa1, VF[dt][1], Oacc[MT][dt], 0, 0, 0);                             \
    }                                                                           \
    __builtin_amdgcn_s_setprio(0); }

    // prologue: stage pair 0 into slots {0,1}, prefetch pair 1
    LOAD_PAIR(0);
    WRITE_PAIR(0);
    if (npair > 1) LOAD_PAIR(1);
    __syncthreads();

    for (int p = 0; p < npair; ++p) {
        const int sb = (p & 1) * 2;        // slot base of current pair
        const int kbA = p * 128;
        const int kbB = kbA + 64;

        // V fragments for sub A (data valid past the barrier)
        short8 VfA[4][2];
#pragma unroll
        for (int dt = 0; dt < 4; dt++)
#pragma unroll
            for (int kc = 0; kc < 2; kc++)
                VfA[dt][kc] = *(const short8*)&Vt[sb * VT_SLOT
                    + vt_idx(dt * 16 + l, kc * 32 + quad * 8)];

        // stage NEXT pair into the other slots (overlaps compute below)
        if (p + 1 < npair) {
            WRITE_PAIR(sb ^ 2);
            if (p + 2 < npair) LOAD_PAIR(p + 2);
        }

        const int qmin0 = q0 + (w << 4);
        const bool act0A = (kbA <= qmin0 + 15);
        const bool act0B = (kbB <= qmin0 + 15);

        // two independent QK chains (shared nothing; scheduler interleaves)
        floatx4 S1A[4], S0A[4], S1B[4], S0B[4];
        QK(sb,     S1A, S0A, act0A);
        QK(sb + 1, S1B, S0B, act0B);

        // softmax+PV A (PV_A MFMAs overlap SM_B VALU), then B
        SM_PV(S1A, 1, kbA, VfA);
        if (act0A) SM_PV(S0A, 0, kbA, VfA);

        short8 VfB[4][2];
#pragma unroll
        for (int dt = 0; dt < 4; dt++)
#pragma unroll
            for (int kc = 0; kc < 2; kc++)
                VfB[dt][kc] = *(const short8*)&Vt[(sb + 1) * VT_SLOT
                    + vt_idx(dt * 16 + l, kc * 32 + quad * 8)];

        SM_PV(S1B, 1, kbB, VfB);
        if (act0B) SM_PV(S0B, 0, kbB, VfB);

        __syncthreads();   // single barrier per 128-key pair
    }

    // epilogue: L lives at lane (q-row & 15); fetch per output row via shfl
#pragma unroll
    for (int mt = 0; mt < 2; mt++)
#pragma unroll
        for (int r = 0; r < 4; r++) {
            const float Lr = __shfl(Lacc[mt], quad * 4 + r);
            const float rl = 1.f / Lr;
            const int qrow = q0 + mt * 64 + (w << 4) + quad * 4 + r;
#pragma unroll
            for (int dt = 0; dt < 4; dt++)
                yatt[(size_t)(b * Tt + qrow) * Cc + h * 64 + dt * 16 + l] =
                    f2bf(Oacc[mt][dt][r] * rl);
        }
#undef LOAD_PAIR
#undef WRITE_TILE
#undef WRITE_PAIR
#undef QK
#undef SM_PV
}

extern "C" void kernel_launch(void* const* d_in, const int* in_sizes, int n_in,
                              void* d_out, int out_size, void* d_ws, size_t ws_size,
                              hipStream_t stream) {
    const float* x     = (const float*)d_in[0];
    const float* Wqkv  = (const float*)d_in[1];
    const float* bqkv  = (const float*)d_in[2];
    const float* Wproj = (const float*)d_in[3];
    const float* bproj = (const float*)d_in[4];
    float* out = (float*)d_out;

    ushort_t* qkvb   = (ushort_t*)d_ws;
    ushort_t* yattb  = qkvb + (size_t)8192 * 3072;
    ushort_t* xb     = yattb + (size_t)8192 * 1024;
    ushort_t* wqkvt  = xb + (size_t)8192 * 1024;
    ushort_t* wprojt = wqkvt + (size_t)3072 * 1024;

    convert_kernel<<<(8192 * 1024 / 4 + 255) / 256, 256, 0, stream>>>(x, xb, 8192 * 1024 / 4);
    transpose_kernel<<<dim3(3072 / 64, 1024 / 16), 256, 0, stream>>>(Wqkv, wqkvt, 1024, 3072);
    transpose_kernel<<<dim3(1024 / 64, 1024 / 16), 256, 0, stream>>>(Wproj, wprojt, 1024, 1024);

    gemm128_kernel<true, true><<<dim3(3072 / 256, 8192 / 128), 512, 0, stream>>>(
        xb, wqkvt, bqkv, qkvb, 8192, 3072, 1024);
    attn_mfma_kernel<<<dim3(64, 16), 256, 0, stream>>>(qkvb, yattb);
    gemm128_kernel<false, false><<<dim3(1024 / 256, 8192 / 128), 512, 0, stream>>>(
        yattb, wprojt, bproj, out, 8192, 1024, 1024);
}

// Round 11
// 252.989 us; speedup vs baseline: 1.0128x; 1.0128x over previous
//
#include <hip/hip_runtime.h>
#include <math.h>

#define Bb 4
#define Tt 2048
#define Cc 1024
#define Hh 16
#define Dd 64
#define QSC 0.18033688011112042f   // (1/sqrt(64)) * log2(e)

typedef unsigned short ushort_t;
typedef __attribute__((ext_vector_type(8))) short short8;
typedef __attribute__((ext_vector_type(4))) float floatx4;

typedef unsigned int __attribute__((address_space(1))) u32_as1;
typedef unsigned int __attribute__((address_space(3))) u32_as3;

__device__ __forceinline__ void gld_lds16(const void* g, const void* lds_uniform) {
    __builtin_amdgcn_global_load_lds(
        (const u32_as1*)(unsigned long long)g,
        (u32_as3*)(unsigned int)(unsigned long long)lds_uniform,
        16, 0, 0);
}

__device__ inline ushort_t f2bf(float x) {
    unsigned int u = __float_as_uint(x);
    return (ushort_t)((u + 0x7FFFu + ((u >> 16) & 1u)) >> 16);
}

__device__ __forceinline__ void bar() {
    asm volatile("" ::: "memory");
    __builtin_amdgcn_s_barrier();
    asm volatile("" ::: "memory");
}

// ---------------- x fp32 -> bf16 ----------------
__global__ __launch_bounds__(256) void convert_kernel(
    const float* __restrict__ in, ushort_t* __restrict__ out, int n4)
{
    int i = blockIdx.x * 256 + threadIdx.x;
    if (i < n4) {
        float4 v = *(const float4*)&in[i * 4];
        ushort_t o[4] = {f2bf(v.x), f2bf(v.y), f2bf(v.z), f2bf(v.w)};
        *(uint2*)&out[i * 4] = *(uint2*)o;
    }
}

// ---------------- W [K][N] fp32 -> Wt [N][K] bf16 ----------------
__global__ __launch_bounds__(256) void transpose_kernel(
    const float* __restrict__ W, ushort_t* __restrict__ Wt, int K, int N)
{
    __shared__ ushort_t Ts[16][72];
    const int n0 = blockIdx.x * 64;
    const int k0 = blockIdx.y * 16;
    const int t = threadIdx.x;
#pragma unroll
    for (int i = 0; i < 4; i++) {
        int e = t + i * 256;
        int kl = e >> 6, nl = e & 63;
        Ts[kl][nl] = f2bf(W[(size_t)(k0 + kl) * N + n0 + nl]);
    }
    __syncthreads();
    {
        int nl = t >> 2, kl4 = (t & 3) * 4;
        ushort_t o[4] = {Ts[kl4][nl], Ts[kl4 + 1][nl], Ts[kl4 + 2][nl], Ts[kl4 + 3][nl]};
        *(uint2*)&Wt[(size_t)(n0 + nl) * K + k0 + kl4] = *(uint2*)o;
    }
}

// ---------------- 128x256 single-barrier bf16 MFMA GEMM ----------------
// Round-11 restructure: every prior GEMM variant (128^2, 256^2 4-phase,
// 128x256 2-phase) plateaued at 687-715 TF (29% peak) — the barrier PAIR per
// 16-MFMA phase lockstepped all 8 waves into the same sub-phase, so ds_read
// windows never overlapped other waves' MFMA windows. Now: ONE barrier per
// K-tile. Iter g: issue all 6 gld_lds of tile g+1 into slot^1 (disjoint from
// slot being read), 12 ds_reads + 32 MFMA of tile g, vmcnt(0) + barrier.
// Between barriers waves free-run => cross-wave DS/MFMA overlap. vmcnt(0)
// drain is cheap: loads issued ~1500 cyc earlier (mostly L2-hit).
template <bool OUT_BF16, bool SCALE_Q>
__global__ __launch_bounds__(512) void gemm128_kernel(
    const ushort_t* __restrict__ A, const ushort_t* __restrict__ Bt,
    const float* __restrict__ bias, void* __restrict__ Co,
    int M, int N, int K)
{
    __shared__ __align__(16) ushort_t Ls[49152];   // 96 KiB: 2 slots x 3 x 8192

    const int tid = threadIdx.x;
    const int lane = tid & 63;
    const int w = tid >> 6;              // 0..7
    const int wm = w >> 2, wn = w & 3;   // wave grid 2m x 4n
    const int l = lane & 15, q = lane >> 4;
    const int NT = K >> 6;               // K-tiles of 64

    const int n0 = blockIdx.x * 256;
    const int m0 = blockIdx.y * 128;

    const int ln = lane ^ (((lane >> 5) & 1) << 1);
    const ushort_t* Ag = A  + (size_t)(m0 + w * 16 + (ln >> 2)) * K + (ln & 3) * 8;
    const ushort_t* Bg = Bt + (size_t)(n0 + w * 16 + (ln >> 2)) * K + (ln & 3) * 8;

    const int swz = l * 32 + ((q * 8) ^ (((l >> 3) & 1) << 4));

    floatx4 acc[2][4][2];
#pragma unroll
    for (int qn = 0; qn < 2; qn++)
#pragma unroll
        for (int mf = 0; mf < 4; mf++)
#pragma unroll
            for (int nf = 0; nf < 2; nf++)
                acc[qn][mf][nf] = (floatx4){0.f, 0.f, 0.f, 0.f};

    short8 af[4][2], bf0[2][2], bf1[2][2];

#define STAGE_A(SLOT, T) {                                                      \
    const ushort_t* _g = Ag + (size_t)(T) * 64;                                 \
    const ushort_t* _l = &Ls[(SLOT) * 24576 + w * 1024];                        \
    gld_lds16(_g, _l);                                                          \
    gld_lds16(_g + 32, _l + 512); }
#define STAGE_B(SLOT, H, T) {                                                   \
    const ushort_t* _g = Bg + (size_t)(H) * 128 * K + (size_t)(T) * 64;         \
    const ushort_t* _l = &Ls[(SLOT) * 24576 + (1 + (H)) * 8192 + w * 1024];     \
    gld_lds16(_g, _l);                                                          \
    gld_lds16(_g + 32, _l + 512); }

#define LDA(SLOT) {                                                             \
    _Pragma("unroll") for (int mf = 0; mf < 4; mf++)                            \
    _Pragma("unroll") for (int kc = 0; kc < 2; kc++)                            \
        af[mf][kc] = *(const short8*)&Ls[(SLOT) * 24576 +                       \
            ((wm * 4 + mf) * 2 + kc) * 512 + swz]; }

#define LDB(SLOT, QN, DST) {                                                    \
    _Pragma("unroll") for (int nf = 0; nf < 2; nf++)                            \
    _Pragma("unroll") for (int kc = 0; kc < 2; kc++)                            \
        DST[nf][kc] = *(const short8*)&Ls[(SLOT) * 24576 + (1 + (QN)) * 8192 +  \
            ((wn * 2 + nf) * 2 + kc) * 512 + swz]; }

#define MM(QN, BF) {                                                            \
    __builtin_amdgcn_s_setprio(1);                                              \
    _Pragma("unroll") for (int kc = 0; kc < 2; kc++)                            \
    _Pragma("unroll") for (int mf = 0; mf < 4; mf++)                            \
    _Pragma("unroll") for (int nf = 0; nf < 2; nf++)                            \
        acc[QN][mf][nf] = __builtin_amdgcn_mfma_f32_16x16x32_bf16(              \
            af[mf][kc], BF[nf][kc], acc[QN][mf][nf], 0, 0, 0);                  \
    __builtin_amdgcn_s_setprio(0); }

#define LGKM0() asm volatile("s_waitcnt lgkmcnt(0)" ::: "memory")

    // prologue: stage tile 0 into slot 0, drain, barrier
    STAGE_A(0, 0); STAGE_B(0, 0, 0); STAGE_B(0, 1, 0);
    asm volatile("s_waitcnt vmcnt(0)" ::: "memory");
    bar();

    for (int g = 0; g < NT; ++g) {
        const int slot = g & 1;

        // issue next tile's staging first (targets slot^1 — no conflict)
        if (g + 1 < NT) {
            STAGE_A(slot ^ 1, g + 1);
            STAGE_B(slot ^ 1, 0, g + 1);
            STAGE_B(slot ^ 1, 1, g + 1);
        }

        // read current tile's fragments and compute both quadrants
        LDA(slot);
        LDB(slot, 0, bf0);
        LDB(slot, 1, bf1);
        LGKM0();
        MM(0, bf0);
        MM(1, bf1);

        // single barrier per K-tile: own loads landed + all waves done reading
        if (g + 1 < NT) {
            asm volatile("s_waitcnt vmcnt(0)" ::: "memory");
            bar();
        }
    }

    // epilogue
#pragma unroll
    for (int qn = 0; qn < 2; qn++)
#pragma unroll
        for (int nf = 0; nf < 2; nf++) {
            const int col = n0 + qn * 128 + wn * 32 + nf * 16 + l;
            const float bi = bias[col];
            const float sc = (SCALE_Q && col < 1024) ? QSC : 1.0f;
#pragma unroll
            for (int mf = 0; mf < 4; mf++)
#pragma unroll
                for (int r = 0; r < 4; r++) {
                    const int row = m0 + wm * 64 + mf * 16 + q * 4 + r;
                    const float v = (acc[qn][mf][nf][r] + bi) * sc;
                    if (OUT_BF16)
                        ((ushort_t*)Co)[(size_t)row * N + col] = f2bf(v);
                    else
                        ((float*)Co)[(size_t)row * N + col] = v;
                }
        }
#undef STAGE_A
#undef STAGE_B
#undef LDA
#undef LDB
#undef MM
#undef LGKM0
}

// ---------------- attn LDS swizzle helpers ----------------
__device__ __forceinline__ int ks_swz(int I) {
    return I ^ (((I >> 8) & 1) * 0x28) ^ (((I >> 9) & 1) * 0x10);
}
__device__ __forceinline__ int vt_idx(int row, int col) {
    return row * 80 + (col ^ ((((row >> 2) ^ (row >> 4)) & 3) << 3));
}

#define KS_SLOT 4096   // ushorts per Ks slot (64 keys x 64 d)
#define VT_SLOT 5120   // ushorts per Vt slot (64 d-rows x 80 stride)

// ---------------- bf16 MFMA flash attention: swapped-QK, KVBLK=128 pairs ----
// (unchanged from round 10 — attn dropped out of top-5 at <72 us)
__global__ __launch_bounds__(256, 2) void attn_mfma_kernel(
    const ushort_t* __restrict__ qkv, ushort_t* __restrict__ yatt)
{
    __shared__ __align__(16) ushort_t Ks[4 * KS_SLOT];
    __shared__ __align__(16) ushort_t Vt[4 * VT_SLOT];

    const int tid = threadIdx.x;
    const int lane = tid & 63;
    const int w = tid >> 6;
    const int quad = lane >> 4;
    const int l = lane & 15;

    const int bh = blockIdx.x;
    const int j = 15 - (int)blockIdx.y;        // heavy-first dispatch
    const int q0 = j * 128;
    const int b = bh >> 4;
    const int h = bh & 15;
    const size_t base = (size_t)b * Tt * (3 * Cc);
    const int qoff = h * 64;
    const int koff = Cc + h * 64;
    const int voff = 2 * Cc + h * 64;

    // Q fragments (pre-scaled by QSC in the GEMM epilogue)
    short8 Qf[2][2];
#pragma unroll
    for (int mt = 0; mt < 2; mt++)
#pragma unroll
        for (int kc = 0; kc < 2; kc++)
            Qf[mt][kc] = *(const short8*)&qkv[base
                + (size_t)(q0 + mt * 64 + w * 16 + l) * (3 * Cc)
                + qoff + kc * 32 + quad * 8];

    floatx4 Oacc[2][4];
    float Lacc[2] = {0.f, 0.f};
#pragma unroll
    for (int mt = 0; mt < 2; mt++)
#pragma unroll
        for (int dt = 0; dt < 4; dt++)
            Oacc[mt][dt] = (floatx4){0.f, 0.f, 0.f, 0.f};

    const int srow = tid >> 2;            // key row 0..63 within a sub-tile
    const int sd0 = (tid & 3) * 16;       // d chunk
    const int knt = srow >> 4, kl = srow & 15;
    const int kc_s = sd0 >> 5;
    const int qp0 = (sd0 & 31) >> 3;
    // PV contraction permutation: key srow stored at column pcol
    const int pcol = 32 * (srow >> 5) + 8 * ((srow >> 2) & 3)
                   + 4 * ((srow >> 4) & 1) + (srow & 3);

    const int npair = j + 1;              // ntil = 2j+2, always even

    const ushort_t* kp0 = &qkv[base + (size_t)srow * (3 * Cc) + koff + sd0];
    const ushort_t* vp0 = &qkv[base + (size_t)srow * (3 * Cc) + voff + sd0];

    const int ksw0 = ks_swz((knt * 2 + kc_s) * 512 + (qp0 * 16 + kl) * 8);
    const int ksw1 = ks_swz((knt * 2 + kc_s) * 512 + ((qp0 + 1) * 16 + kl) * 8);

    uint4 pk00, pk01, pv00, pv01;   // sub A prefetch
    uint4 pk10, pk11, pv10, pv11;   // sub B prefetch

#define LOAD_PAIR(P) {                                                          \
    const size_t _o0 = (size_t)((P) * 128) * (3 * Cc);                          \
    const size_t _o1 = _o0 + (size_t)64 * (3 * Cc);                             \
    pk00 = *(const uint4*)(kp0 + _o0); pk01 = *(const uint4*)(kp0 + _o0 + 8);   \
    pv00 = *(const uint4*)(vp0 + _o0); pv01 = *(const uint4*)(vp0 + _o0 + 8);   \
    pk10 = *(const uint4*)(kp0 + _o1); pk11 = *(const uint4*)(kp0 + _o1 + 8);   \
    pv10 = *(const uint4*)(vp0 + _o1); pv11 = *(const uint4*)(vp0 + _o1 + 8); }

#define WRITE_TILE(SLOT, PK0, PK1, PV0, PV1) {                                  \
    *(uint4*)&Ks[(SLOT) * KS_SLOT + ksw0] = PK0;                                \
    *(uint4*)&Ks[(SLOT) * KS_SLOT + ksw1] = PK1;                                \
    ushort_t tv[16];                                                            \
    *(uint4*)&tv[0] = PV0;                                                      \
    *(uint4*)&tv[8] = PV1;                                                      \
    _Pragma("unroll") for (int t2 = 0; t2 < 16; t2++)                           \
        Vt[(SLOT) * VT_SLOT + vt_idx(sd0 + t2, pcol)] = tv[t2]; }

#define WRITE_PAIR(SB) {                                                        \
    WRITE_TILE((SB), pk00, pk01, pv00, pv01);                                   \
    WRITE_TILE((SB) + 1, pk10, pk11, pv10, pv11); }

// swapped QK^T over one 64-key sub-tile in LDS slot SLOT
#define QK(SLOT, S1, S0, ACT0) {                                                \
    _Pragma("unroll") for (int nt = 0; nt < 4; nt++)                            \
        S1[nt] = (floatx4){0.f, 0.f, 0.f, 0.f};                                 \
    __builtin_amdgcn_s_setprio(1);                                              \
    if (ACT0) {                                                                 \
        _Pragma("unroll") for (int nt = 0; nt < 4; nt++)                        \
            S0[nt] = (floatx4){0.f, 0.f, 0.f, 0.f};                             \
        _Pragma("unroll") for (int kc = 0; kc < 2; kc++)                        \
        _Pragma("unroll") for (int nt = 0; nt < 4; nt++) {                      \
            short8 kf = *(const short8*)&Ks[(SLOT) * KS_SLOT                    \
                + ks_swz((nt * 2 + kc) * 512 + lane * 8)];                      \
            S1[nt] = __builtin_amdgcn_mfma_f32_16x16x32_bf16(                   \
                kf, Qf[1][kc], S1[nt], 0, 0, 0);                                \
            S0[nt] = __builtin_amdgcn_mfma_f32_16x16x32_bf16(                   \
                kf, Qf[0][kc], S0[nt], 0, 0, 0);                                \
        }                                                                       \
    } else {                                                                    \
        _Pragma("unroll") for (int kc = 0; kc < 2; kc++)                        \
        _Pragma("unroll") for (int nt = 0; nt < 4; nt++) {                      \
            short8 kf = *(const short8*)&Ks[(SLOT) * KS_SLOT                    \
                + ks_swz((nt * 2 + kc) * 512 + lane * 8)];                      \
            S1[nt] = __builtin_amdgcn_mfma_f32_16x16x32_bf16(                   \
                kf, Qf[1][kc], S1[nt], 0, 0, 0);                                \
        }                                                                       \
    }                                                                           \
    __builtin_amdgcn_s_setprio(0); }

// in-register softmax + PV for one (mt, sub-tile): lane's q-row = qmin + l
#define SM_PV(SV, MT, KB, VF) {                                                 \
    const int qrow = q0 + (MT) * 64 + (w << 4) + l;                             \
    const bool needm = ((KB) + 63 > q0 + (MT) * 64 + (w << 4));                 \
    float lsum = 0.f;                                                           \
    unsigned int pw[8];                                                         \
    _Pragma("unroll") for (int nt = 0; nt < 4; nt++) {                          \
        float e[4];                                                             \
        _Pragma("unroll") for (int r = 0; r < 4; r++) {                         \
            float s2 = SV[nt][r];                                               \
            if (needm && ((KB) + nt * 16 + quad * 4 + r > qrow))                \
                s2 = -INFINITY;                                                 \
            e[r] = __builtin_amdgcn_exp2f(s2);                                  \
            lsum += e[r];                                                       \
        }                                                                       \
        pw[nt * 2 + 0] = __builtin_amdgcn_perm(                                 \
            __float_as_uint(e[1]), __float_as_uint(e[0]), 0x07060302u);         \
        pw[nt * 2 + 1] = __builtin_amdgcn_perm(                                 \
            __float_as_uint(e[3]), __float_as_uint(e[2]), 0x07060302u);         \
    }                                                                           \
    lsum += __shfl_xor(lsum, 16);                                               \
    lsum += __shfl_xor(lsum, 32);                                               \
    Lacc[MT] += lsum;                                                           \
    uint4 _u0; _u0.x = pw[0]; _u0.y = pw[1]; _u0.z = pw[2]; _u0.w = pw[3];      \
    uint4 _u1; _u1.x = pw[4]; _u1.y = pw[5]; _u1.z = pw[6]; _u1.w = pw[7];      \
    short8 Pa0 = __builtin_bit_cast(short8, _u0);                               \
    short8 Pa1 = __builtin_bit_cast(short8, _u1);                               \
    __builtin_amdgcn_s_setprio(1);                                              \
    _Pragma("unroll") for (int dt = 0; dt < 4; dt++) {                          \
        Oacc[MT][dt] = __builtin_amdgcn_mfma_f32_16x16x32_bf16(                 \
            Pa0, VF[dt][0], Oacc[MT][dt], 0, 0, 0);                             \
        Oacc[MT][dt] = __builtin_amdgcn_mfma_f32_16x16x32_bf16(                 \
            Pa1, VF[dt][1], Oacc[MT][dt], 0, 0, 0);                             \
    }                                                                           \
    __builtin_amdgcn_s_setprio(0); }

    // prologue: stage pair 0 into slots {0,1}, prefetch pair 1
    LOAD_PAIR(0);
    WRITE_PAIR(0);
    if (npair > 1) LOAD_PAIR(1);
    __syncthreads();

    for (int p = 0; p < npair; ++p) {
        const int sb = (p & 1) * 2;        // slot base of current pair
        const int kbA = p * 128;
        const int kbB = kbA + 64;

        // V fragments for sub A (data valid past the barrier)
        short8 VfA[4][2];
#pragma unroll
        for (int dt = 0; dt < 4; dt++)
#pragma unroll
            for (int kc = 0; kc < 2; kc++)
                VfA[dt][kc] = *(const short8*)&Vt[sb * VT_SLOT
                    + vt_idx(dt * 16 + l, kc * 32 + quad * 8)];

        // stage NEXT pair into the other slots (overlaps compute below)
        if (p + 1 < npair) {
            WRITE_PAIR(sb ^ 2);
            if (p + 2 < npair) LOAD_PAIR(p + 2);
        }

        const int qmin0 = q0 + (w << 4);
        const bool act0A = (kbA <= qmin0 + 15);
        const bool act0B = (kbB <= qmin0 + 15);

        // two independent QK chains (shared nothing; scheduler interleaves)
        floatx4 S1A[4], S0A[4], S1B[4], S0B[4];
        QK(sb,     S1A, S0A, act0A);
        QK(sb + 1, S1B, S0B, act0B);

        // softmax+PV A (PV_A MFMAs overlap SM_B VALU), then B
        SM_PV(S1A, 1, kbA, VfA);
        if (act0A) SM_PV(S0A, 0, kbA, VfA);

        short8 VfB[4][2];
#pragma unroll
        for (int dt = 0; dt < 4; dt++)
#pragma unroll
            for (int kc = 0; kc < 2; kc++)
                VfB[dt][kc] = *(const short8*)&Vt[(sb + 1) * VT_SLOT
                    + vt_idx(dt * 16 + l, kc * 32 + quad * 8)];

        SM_PV(S1B, 1, kbB, VfB);
        if (act0B) SM_PV(S0B, 0, kbB, VfB);

        __syncthreads();   // single barrier per 128-key pair
    }

    // epilogue: L lives at lane (q-row & 15); fetch per output row via shfl
#pragma unroll
    for (int mt = 0; mt < 2; mt++)
#pragma unroll
        for (int r = 0; r < 4; r++) {
            const float Lr = __shfl(Lacc[mt], quad * 4 + r);
            const float rl = 1.f / Lr;
            const int qrow = q0 + mt * 64 + (w << 4) + quad * 4 + r;
#pragma unroll
            for (int dt = 0; dt < 4; dt++)
                yatt[(size_t)(b * Tt + qrow) * Cc + h * 64 + dt * 16 + l] =
                    f2bf(Oacc[mt][dt][r] * rl);
        }
#undef LOAD_PAIR
#undef WRITE_TILE
#undef WRITE_PAIR
#undef QK
#undef SM_PV
}

extern "C" void kernel_launch(void* const* d_in, const int* in_sizes, int n_in,
                              void* d_out, int out_size, void* d_ws, size_t ws_size,
                              hipStream_t stream) {
    const float* x     = (const float*)d_in[0];
    const float* Wqkv  = (const float*)d_in[1];
    const float* bqkv  = (const float*)d_in[2];
    const float* Wproj = (const float*)d_in[3];
    const float* bproj = (const float*)d_in[4];
    float* out = (float*)d_out;

    ushort_t* qkvb   = (ushort_t*)d_ws;
    ushort_t* yattb  = qkvb + (size_t)8192 * 3072;
    ushort_t* xb     = yattb + (size_t)8192 * 1024;
    ushort_t* wqkvt  = xb + (size_t)8192 * 1024;
    ushort_t* wprojt = wqkvt + (size_t)3072 * 1024;

    convert_kernel<<<(8192 * 1024 / 4 + 255) / 256, 256, 0, stream>>>(x, xb, 8192 * 1024 / 4);
    transpose_kernel<<<dim3(3072 / 64, 1024 / 16), 256, 0, stream>>>(Wqkv, wqkvt, 1024, 3072);
    transpose_kernel<<<dim3(1024 / 64, 1024 / 16), 256, 0, stream>>>(Wproj, wprojt, 1024, 1024);

    gemm128_kernel<true, true><<<dim3(3072 / 256, 8192 / 128), 512, 0, stream>>>(
        xb, wqkvt, bqkv, qkvb, 8192, 3072, 1024);
    attn_mfma_kernel<<<dim3(64, 16), 256, 0, stream>>>(qkvb, yattb);
    gemm128_kernel<false, false><<<dim3(1024 / 256, 8192 / 128), 512, 0, stream>>>(
        yattb, wprojt, bproj, out, 8192, 1024, 1024);
}